// Round 6
// baseline (119.909 us; speedup 1.0000x reference)
//
#include <hip/hip_runtime.h>
#include <hip/hip_bf16.h>
#include <stdint.h>

// ---- problem constants ----
#define C_CLS  100000
#define DDIM   512
#define BROWS  512
#define NT     64          // classes per tile
#define EPSN   1e-5f
#define GRID_G 512         // gemm grid (2 blocks/CU); tiles interleaved by GRID_G

typedef __attribute__((ext_vector_type(8))) short short8;
typedef __attribute__((ext_vector_type(4))) float f32x4;

// d_ws float layout:
//   [0    .. 4096)  : 256 gemm accumulation slots, stride 16 floats
//   [4096 .. 5120)  : 64 label accumulation slots, stride 16 floats
//   byte 32768 ...  : xnf — bf16 A in MFMA fragment layout (512 KB)

__device__ inline unsigned pk2(float a, float b) {
  __hip_bfloat162 h = __float22bfloat162_rn(make_float2(a, b));
  unsigned u; __builtin_memcpy(&u, &h, 4); return u;
}

// Normalize each input row -> bf16, fragment order:
// cell idx (16B) = (s*32 + r16)*64 + khalf*16 + row; s=k>>5, r16=b>>4,
// khalf=(k>>3)&3, row=b&15. Also zeroes the ws accumulation slots.
__global__ void __launch_bounds__(64) k_norm_input(const float* __restrict__ in,
                                                   uint4* __restrict__ xnf,
                                                   float* __restrict__ ws) {
  int b = blockIdx.x;
  int lane = threadIdx.x;              // lane covers k = lane*8 .. +7
  if (lane == 0) {                     // zero accumulation slots
    if (b < 256) ws[b * 16] = 0.f;
    else if (b < 320) ws[4096 + (b - 256) * 16] = 0.f;
  }
  const float4* row = (const float4*)(in + b * DDIM);
  float4 v0 = row[lane * 2];
  float4 v1 = row[lane * 2 + 1];
  float ss = v0.x*v0.x + v0.y*v0.y + v0.z*v0.z + v0.w*v0.w
           + v1.x*v1.x + v1.y*v1.y + v1.z*v1.z + v1.w*v1.w;
#pragma unroll
  for (int o = 32; o >= 1; o >>= 1) ss += __shfl_xor(ss, o, 64);
  float sc = 1.f / fmaxf(sqrtf(ss), EPSN);
  uint4 o4;
  o4.x = pk2(v0.x*sc, v0.y*sc);
  o4.y = pk2(v0.z*sc, v0.w*sc);
  o4.z = pk2(v1.x*sc, v1.y*sc);
  o4.w = pk2(v1.z*sc, v1.w*sc);
  int idx = ((lane >> 2) * 32 + (b >> 4)) * 64 + (lane & 3) * 16 + (b & 15);
  xnf[idx] = o4;
}

// Fused GEMM + loss. 256 threads (4 waves), each wave owns 128 rows (m=8).
// Per block: 3-4 class-tiles of NT=64. W LDS = two half-K buffers (32 KB each);
// half-K software pipeline: compute 8 steps from sH[p&1] while streaming the
// next half's f32 W through regs into sH[(p&1)^1]. A-frags stream from L2.
__global__ void __launch_bounds__(256, 2)
k_gemm(const uint4* __restrict__ xnf, const float* __restrict__ wt,
       const float* __restrict__ bias, float* __restrict__ ws) {
  __shared__ __align__(16) unsigned char sH[2][32768];
  __shared__ float sNsq[2][NT];
  __shared__ float sRed[4];

  const int tid  = threadIdx.x;
  const int lane = tid & 63;
  const int wv   = tid >> 6;                 // 0..3, rows [wv*128, +128)
  const int b    = blockIdx.x;               // 0..511
  const int ntile = (b < 27) ? 4 : 3;        // 1563 = 3*512 + 27
  const int P = ntile * 2;                   // half-K phases

  // W staging: thread t owns class c_loc = t>>2, sub-quads q = (t&3) + 4j
  const int c_loc = tid >> 2;
  const int sub   = tid & 3;
  const int rbyte = (lane * 16) ^ (((lane >> 4) & 3) << 4);  // frag read, XOR-swz

  float wsq = 0.f, lsum = 0.f;
  const float bv = bias[0];

  // write one 8-quad batch into a half-buffer (frag layout + XOR swizzle)
  auto stage_write = [&](unsigned char* dst, const float4* wr, int batch) {
#pragma unroll
    for (int j = 0; j < 8; ++j) {
      int q = sub + 4 * (batch * 8 + j);      // quad within the K-half (0..63)
      int kh = (q >> 1) & 3;
      int cell = (c_loc >> 4) * 64 + kh * 16 + (c_loc & 15);
      int byte = (q >> 3) * 4096 + ((cell * 16) ^ (kh << 4)) + (q & 1) * 8;
      float4 w = wr[j];
      wsq += w.x*w.x + w.y*w.y + w.z*w.z + w.w*w.w;
      uint2 d; d.x = pk2(w.x, w.y); d.y = pk2(w.z, w.w);
      *(uint2*)(dst + byte) = d;
    }
  };

  // prologue: stage (tile 0, K-low) into sH[0]
  {
    int cls = b * NT + c_loc;
    if (cls >= C_CLS) cls = C_CLS - 1;
    const float4* src = (const float4*)(wt + (size_t)cls * DDIM);
    float4 wr[8];
#pragma unroll
    for (int j = 0; j < 8; ++j) wr[j] = src[sub + 4 * j];
    stage_write(sH[0], wr, 0);
#pragma unroll
    for (int j = 0; j < 8; ++j) wr[j] = src[sub + 4 * (8 + j)];
    stage_write(sH[0], wr, 1);
  }

  f32x4 acc[8][4];
#pragma unroll
  for (int m = 0; m < 8; ++m)
#pragma unroll
    for (int n = 0; n < 4; ++n) acc[m][n] = (f32x4)(0.f);

  __syncthreads();

#pragma unroll 1
  for (int p = 0; p < P; ++p) {
    const int cur = p & 1;                   // sH buffer to read; h = K-half
    const bool more = (p + 1 < P);
    const float4* src1 = nullptr;
    if (more) {
      int t1 = (p + 1) >> 1, h1 = (p + 1) & 1;
      int cls = (b + t1 * GRID_G) * NT + c_loc;
      if (cls >= C_CLS) cls = C_CLS - 1;
      src1 = (const float4*)(wt + (size_t)cls * DDIM + h1 * 256);
    }
    float4 wr[8];
    if (more) {
#pragma unroll
      for (int j = 0; j < 8; ++j) wr[j] = src1[sub + 4 * j];   // batch 0 in flight
    }
    // steps 0..3 of this K-half
#pragma unroll
    for (int sl = 0; sl < 4; ++sl) {
      int s = cur * 8 + sl;                  // full-K step index
      const uint4* ab = xnf + ((s * 32 + wv * 8) * 64 + lane);
      short8 af[8];
#pragma unroll
      for (int m = 0; m < 8; ++m) af[m] = *(const short8*)(ab + m * 64);
      const unsigned char* Wb = sH[cur] + sl * 4096;
#pragma unroll
      for (int n = 0; n < 4; ++n) {
        short8 wf = *(const short8*)(Wb + n * 1024 + rbyte);
#pragma unroll
        for (int m = 0; m < 8; ++m)
          acc[m][n] = __builtin_amdgcn_mfma_f32_16x16x32_bf16(af[m], wf, acc[m][n], 0, 0, 0);
      }
    }
    if (more) {
      stage_write(sH[cur ^ 1], wr, 0);       // wr long since landed (4 steps)
#pragma unroll
      for (int j = 0; j < 8; ++j) wr[j] = src1[sub + 4 * (8 + j)];  // batch 1
    }
    // steps 4..7
#pragma unroll
    for (int sl = 4; sl < 8; ++sl) {
      int s = cur * 8 + sl;
      const uint4* ab = xnf + ((s * 32 + wv * 8) * 64 + lane);
      short8 af[8];
#pragma unroll
      for (int m = 0; m < 8; ++m) af[m] = *(const short8*)(ab + m * 64);
      const unsigned char* Wb = sH[cur] + sl * 4096;
#pragma unroll
      for (int n = 0; n < 4; ++n) {
        short8 wf = *(const short8*)(Wb + n * 1024 + rbyte);
#pragma unroll
        for (int m = 0; m < 8; ++m)
          acc[m][n] = __builtin_amdgcn_mfma_f32_16x16x32_bf16(af[m], wf, acc[m][n], 0, 0, 0);
      }
    }
    if (cur == 1) {
      // K-half 1 done -> epilogue for tile t (overlaps batch-1 load flight)
      int t = p >> 1;
      int cb = (b + t * GRID_G) * NT;
      const float* nsq = sNsq[t & 1];
#pragma unroll
      for (int n = 0; n < 4; ++n) {
        int cl = n * 16 + (lane & 15);
        float s64 = 64.f / fmaxf(sqrtf(nsq[cl]), EPSN);
        bool valid = (cb + cl) < C_CLS;
#pragma unroll
        for (int m = 0; m < 8; ++m) {
#pragma unroll
          for (int i = 0; i < 4; ++i) {
            // x = 64*cos - bias <= ~51: upper clamp provably inactive; lower
            // clip irrelevant (exp underflow). log1p(z) ~= z - z^2/2, z<=1/32.
            float x = fmaf(acc[m][n][i], s64, -bv);
            float z = __expf(x);
            float l = fmaf(-0.5f * z, z, z);
            if (z > 0.03125f) l = __logf(1.f + z);   // rare (~1e-4)
            lsum += valid ? l : 0.f;
          }
          acc[m][n] = (f32x4)(0.f);
        }
      }
    }
    if (more) {
      stage_write(sH[cur ^ 1], wr, 1);
      if (((p + 1) & 1) == 1) {
        // finished staging K-high of tile t1 = (p+1)>>1: publish its norm^2
        float t2 = wsq + __shfl_xor(wsq, 1, 64);
        t2 += __shfl_xor(t2, 2, 64);
        if (sub == 0) sNsq[((p + 1) >> 1) & 1][c_loc] = t2;
        wsq = 0.f;
      }
    }
    __syncthreads();
  }

  // ---- final loss reduce + one atomic ----
#pragma unroll
  for (int o = 32; o >= 1; o >>= 1) lsum += __shfl_xor(lsum, o, 64);
  if (lane == 0) sRed[wv] = lsum;
  __syncthreads();
  if (tid == 0)
    atomicAdd(&ws[(b & 255) * 16], sRed[0] + sRed[1] + sRed[2] + sRed[3]);
}

// Label correction: replace n_loss(b, label_b) by p_loss(b, label_b), full f32.
__global__ void __launch_bounds__(64) k_label(const float* __restrict__ in,
                                              const float* __restrict__ wt,
                                              const int* __restrict__ label,
                                              const float* __restrict__ bias,
                                              float* __restrict__ ws) {
  int b = blockIdx.x;
  int lane = threadIdx.x;
  int c = label[b];
  const float4* xr = (const float4*)(in + b * DDIM);
  const float4* wr = (const float4*)(wt + (size_t)c * DDIM);
  float dt = 0.f, sx = 0.f, sw = 0.f;
#pragma unroll
  for (int i = 0; i < 2; i++) {
    float4 x = xr[lane * 2 + i];
    float4 w = wr[lane * 2 + i];
    dt += x.x*w.x + x.y*w.y + x.z*w.z + x.w*w.w;
    sx += x.x*x.x + x.y*x.y + x.z*x.z + x.w*x.w;
    sw += w.x*w.x + w.y*w.y + w.z*w.z + w.w*w.w;
  }
#pragma unroll
  for (int o = 32; o >= 1; o >>= 1) {
    dt += __shfl_xor(dt, o, 64);
    sx += __shfl_xor(sx, o, 64);
    sw += __shfl_xor(sw, o, 64);
  }
  if (lane == 0) {
    float bv = bias[0];
    float cosv = dt / (fmaxf(sqrtf(sx), EPSN) * fmaxf(sqrtf(sw), EPSN));
    float cp = 64.f * (cosv - 0.4f) - bv;
    cp = fminf(fmaxf(cp, -64.f), 64.f);
    float pl = log1pf(expf(-cp));
    float cn = 64.f * cosv - bv;
    cn = fminf(fmaxf(cn, -64.f), 64.f);
    float nl = log1pf(expf(cn));
    atomicAdd(&ws[4096 + (b & 63) * 16], pl - nl);
  }
}

// Merge the 256 gemm slots + 64 label slots, scale by 1/B.
__global__ void __launch_bounds__(64) k_final(const float* __restrict__ ws,
                                              float* __restrict__ out) {
  int lane = threadIdx.x;
  float s = ws[lane * 16] + ws[(lane + 64) * 16]
          + ws[(lane + 128) * 16] + ws[(lane + 192) * 16]
          + ws[4096 + lane * 16];
#pragma unroll
  for (int o = 32; o >= 1; o >>= 1) s += __shfl_xor(s, o, 64);
  if (lane == 0) out[0] = s * (1.f / 512.f);
}

extern "C" void kernel_launch(void* const* d_in, const int* in_sizes, int n_in,
                              void* d_out, int out_size, void* d_ws, size_t ws_size,
                              hipStream_t stream) {
  const float* input  = (const float*)d_in[0];
  const int*   label  = (const int*)d_in[1];
  const float* weight = (const float*)d_in[2];
  const float* bias   = (const float*)d_in[3];
  float* out = (float*)d_out;
  float* ws  = (float*)d_ws;
  uint4* xnf = (uint4*)((char*)d_ws + 32768);

  k_norm_input<<<BROWS, 64, 0, stream>>>(input, xnf, ws);
  k_gemm<<<GRID_G, 256, 0, stream>>>(xnf, weight, bias, ws);
  k_label<<<BROWS, 64, 0, stream>>>(input, weight, label, bias, ws);
  k_final<<<1, 64, 0, stream>>>(ws, out);
}